// Round 2
// baseline (441.438 us; speedup 1.0000x reference)
//
#include <hip/hip_runtime.h>
#include <math.h>

#define NH 32
#define NKVH 8
#define HD 128

typedef _Float16 half8 __attribute__((ext_vector_type(8)));
typedef float f32x4 __attribute__((ext_vector_type(4)));

// ws layout (float elements):
#define OFF_QPROJ 0        // 4096 q | 1024 k | 1024 v
#define OFF_KNEW  4096
#define OFF_VNEW  5120
#define OFF_QR    6144     // 4096
#define OFF_QHASH 10240    // 128 (32x u32)
#define OFF_TAB   10368    // cos K*64 | sin K*64
// OFF_SCORES = OFF_TAB + 2*K*64        (NH*K floats)
// OFF_DRAFT  = OFF_SCORES + NH*K       (NH*K int)
// OFF_ATTN   = OFF_DRAFT + NH*K        (4096)
// OFF_SELIDX = OFF_ATTN + 4096         (NH*512 int)
// OFF_SELW   = OFF_SELIDX + NH*512     (NH*512)
// OFF_PT16   = OFF_SELW + NH*512       (NH*2*16384 fp16)

// combined: rope tables + zero-init (blocks < nInit), PT16 weight transpose
// (blocks >= nInit). PT16[h][mat][ks(4)][nt(8)][lane(64)][j(8)] =
// P[h][k=ks*32+(lane>>4)*8+j][n=nt*16+(lane&15)]
__global__ void init_kernel(const float* __restrict__ hp1, const float* __restrict__ hp2,
                            float* __restrict__ ws, float* __restrict__ out,
                            int K, int nInit) {
    const int tid = threadIdx.x;
    if ((int)blockIdx.x < nInit) {
        int idx = blockIdx.x * 256 + tid;
        if (idx < K * 64) {
            int pos = idx >> 6, d = idx & 63;
            double inv = exp(-((double)d / 64.0) * log(10000.0));
            double ang = (double)pos * inv;
            double s, c;
            sincos(ang, &s, &c);
            ws[OFF_TAB + idx]                  = (float)c;
            ws[OFF_TAB + (size_t)K * 64 + idx] = (float)s;
        }
        if (idx < 6144) ws[OFF_QPROJ + idx] = 0.f;
        if (idx < 4096) out[idx] = 0.f;
        size_t off_attn = OFF_TAB + 2 * (size_t)K * 64 + 2 * (size_t)NH * K;
        if (idx < 4096) ws[off_attn + idx] = 0.f;
    } else {
        int id = blockIdx.x - nInit;          // 0..511
        int h2 = id >> 3;                     // 0..63  (h*2+mat)
        int tg = (id & 7) * 256 + tid;        // 0..2047
        const int lane = tg & 63, nt = (tg >> 6) & 7, ks = tg >> 9;
        const int kbase = ks * 32 + ((tg >> 4) & 3) * 8;
        const int n = nt * 16 + (tg & 15);
        const float* P = ((h2 & 1) ? hp2 : hp1) + (size_t)(h2 >> 1) * 16384;
        half8 v;
#pragma unroll
        for (int j = 0; j < 8; ++j) v[j] = (_Float16)P[(size_t)(kbase + j) * 128 + n];
        size_t off_pt = OFF_TAB + 2 * (size_t)K * 64 + 2 * (size_t)NH * K + 4096 + 2 * (size_t)NH * 512;
        ((half8*)(ws + off_pt))[(size_t)h2 * 2048 + tg] = v;
    }
}

// hidden(4096) @ [Wq|Wk|Wv] -> qproj(6144). float4 cols, 64-row split-K, atomics.
// (r0-measured config; y=128 doubled atomic contention and regressed)
__global__ __launch_bounds__(256) void qkv_gemv(const float* __restrict__ hidden,
        const float* __restrict__ Wq, const float* __restrict__ Wk,
        const float* __restrict__ Wv, float* __restrict__ ws) {
    __shared__ float hs[64];
    const int tid = threadIdx.x;
    const int col = (blockIdx.x * 256 + tid) * 4;
    const int i0  = blockIdx.y * 64;
    if (tid < 64) hs[tid] = hidden[i0 + tid];
    __syncthreads();
    const float* W; int ld, wcol;
    if (col < 4096)      { W = Wq; ld = 4096; wcol = col; }
    else if (col < 5120) { W = Wk; ld = 1024; wcol = col - 4096; }
    else                 { W = Wv; ld = 1024; wcol = col - 5120; }
    const float* p = W + (size_t)i0 * ld + wcol;
    float4 a0 = {0.f,0.f,0.f,0.f}, a1 = {0.f,0.f,0.f,0.f};
#pragma unroll 4
    for (int ii = 0; ii < 64; ii += 2) {
        float4 w0 = *(const float4*)p;
        float4 w1 = *(const float4*)(p + ld);
        float h0 = hs[ii], h1 = hs[ii + 1];
        a0.x = fmaf(h0, w0.x, a0.x); a0.y = fmaf(h0, w0.y, a0.y);
        a0.z = fmaf(h0, w0.z, a0.z); a0.w = fmaf(h0, w0.w, a0.w);
        a1.x = fmaf(h1, w1.x, a1.x); a1.y = fmaf(h1, w1.y, a1.y);
        a1.z = fmaf(h1, w1.z, a1.z); a1.w = fmaf(h1, w1.w, a1.w);
        p += 2 * (size_t)ld;
    }
    atomicAdd(&ws[OFF_QPROJ + col + 0], a0.x + a1.x);
    atomicAdd(&ws[OFF_QPROJ + col + 1], a0.y + a1.y);
    atomicAdd(&ws[OFF_QPROJ + col + 2], a0.z + a1.z);
    atomicAdd(&ws[OFF_QPROJ + col + 3], a0.w + a1.w);
}

// per head: rope(q), hash(q) in fp32, pack sign bits
__global__ __launch_bounds__(128) void qhash_kernel(const float* __restrict__ hp1,
        const float* __restrict__ hb1, const float* __restrict__ hp2,
        const float* __restrict__ hb2, float* __restrict__ ws, int S) {
    const int h = blockIdx.x, d = threadIdx.x;
    const int K = S + 1;
    __shared__ float X[128], H1[128];
    float q  = ws[OFF_QPROJ + h * 128 + d];
    float qp = ws[OFF_QPROJ + h * 128 + (d ^ 64)];
    const float* cosT = ws + OFF_TAB;
    const float* sinT = cosT + (size_t)K * 64;
    float cs = cosT[(size_t)S * 64 + (d & 63)];
    float sn = sinT[(size_t)S * 64 + (d & 63)];
    float r = (d < 64) ? -qp : qp;
    float qr = q * cs + r * sn;
    X[d] = qr;
    ws[OFF_QR + h * 128 + d] = qr;
    __syncthreads();
    const float* P1 = hp1 + (size_t)h * 16384;
    float t = hb1[h * 128 + d];
    for (int i = 0; i < 128; ++i) t = fmaf(X[i], P1[i * 128 + d], t);
    float u = t / (1.f + expf(-t)) + X[d];
    H1[d] = u;
    __syncthreads();
    const float* P2 = hp2 + (size_t)h * 16384;
    float t2 = hb2[h * 128 + d] + u;
    for (int i = 0; i < 128; ++i) t2 = fmaf(H1[i], P2[i * 128 + d], t2);
    unsigned long long bal = __ballot(t2 > 0.f);
    if ((d & 63) == 0)
        ((unsigned long long*)(ws + OFF_QHASH))[h * 2 + (d >> 6)] = bal;
}

// MFMA key kernel, barrier-free, 2-tile software-pipelined: each block does
// 128 keys as two 64-key tiles; tile-B's HBM key loads are issued before
// tile-A's compute so the memory pipe stays busy during GEMM/epilogue phases.
// XF: stride-128 fp32 + XOR swizzle (col ^ ((row&7)<<2)) => 32768 B LDS and
// XOR-distributed start banks on the float4 GEMM2 reads (was 8-way at 132).
__global__ __launch_bounds__(256, 4) void key_kernel(const float* __restrict__ key_cache,
        const float* __restrict__ hb1, const float* __restrict__ hb2,
        float* __restrict__ ws, int S) {
    const int K  = S + 1;
    const int h  = blockIdx.y;
    const int k0 = blockIdx.x * 128;
    const int tid = threadIdx.x;
    const int wv = tid >> 6, lane = tid & 63;
    const int m = lane & 15, quad = lane >> 4;
    const int row = wv * 16 + m;          // row within tile
    const int cbase = quad * 8;
    const int sw = (m & 7) << 2;          // XOR swizzle for this thread's row

    __shared__ float XF[64 * 128];        // 32 KiB

    const float* cosT = ws + OFF_TAB;
    const float* sinT = cosT + (size_t)K * 64;
    float* scores = ws + OFF_TAB + 2 * (size_t)K * 64;
    int*   draft  = (int*)(scores + (size_t)NH * K);
    size_t off_pt = OFF_TAB + 2 * (size_t)K * 64 + 2 * (size_t)NH * K + 4096 + 2 * (size_t)NH * 512;
    const half8* PT1 = (const half8*)((const _Float16*)(ws + off_pt) + (size_t)(h * 2) * 16384);
    const half8* PT2 = PT1 + 2048;

#define LOAD_KEYS(kgv, xv)                                                         \
    if ((kgv) < K) {                                                               \
        const float* krow_ = ((kgv) < S) ? key_cache + ((size_t)h * S + (kgv)) * 128 \
                                         : ws + OFF_KNEW + (h >> 2) * 128;         \
        _Pragma("unroll") for (int c = 0; c < 4; ++c) {                            \
            *(float4*)&(xv)[c][0] = *(const float4*)(krow_ + c * 32 + cbase);      \
            *(float4*)&(xv)[c][4] = *(const float4*)(krow_ + c * 32 + cbase + 4);  \
        }                                                                          \
    } else {                                                                       \
        _Pragma("unroll") for (int c = 0; c < 4; ++c)                              \
            _Pragma("unroll") for (int j = 0; j < 8; ++j) (xv)[c][j] = 0.f;        \
    }

#define ROPE_INPLACE(kgv, xv)                                                      \
    if ((kgv) < K) {                                                               \
        float cc_[2][8], ss_[2][8];                                                \
        _Pragma("unroll") for (int c = 0; c < 2; ++c) {                            \
            *(float4*)&cc_[c][0] = *(const float4*)(cosT + (size_t)(kgv) * 64 + c * 32 + cbase);     \
            *(float4*)&cc_[c][4] = *(const float4*)(cosT + (size_t)(kgv) * 64 + c * 32 + cbase + 4); \
            *(float4*)&ss_[c][0] = *(const float4*)(sinT + (size_t)(kgv) * 64 + c * 32 + cbase);     \
            *(float4*)&ss_[c][4] = *(const float4*)(sinT + (size_t)(kgv) * 64 + c * 32 + cbase + 4); \
        }                                                                          \
        _Pragma("unroll") for (int c = 0; c < 2; ++c)                              \
            _Pragma("unroll") for (int j = 0; j < 8; ++j) {                        \
                float lo_ = (xv)[c][j] * cc_[c][j] - (xv)[c + 2][j] * ss_[c][j];   \
                float hi_ = (xv)[c + 2][j] * cc_[c][j] + (xv)[c][j] * ss_[c][j];   \
                (xv)[c][j] = lo_; (xv)[c + 2][j] = hi_;                            \
            }                                                                      \
    }

#define PROCESS_TILE(xr, ktile)                                                    \
    {                                                                              \
        _Pragma("unroll") for (int c = 0; c < 4; ++c) {                            \
            *(float4*)&XF[row * 128 + ((c * 32 + cbase) ^ sw)]     = *(float4*)&(xr)[c][0]; \
            *(float4*)&XF[row * 128 + ((c * 32 + cbase + 4) ^ sw)] = *(float4*)&(xr)[c][4]; \
        }                                                                          \
        {                                                                          \
            const float* qr_ = ws + OFF_QR + h * 128;                              \
            float part = 0.f;                                                      \
            _Pragma("unroll") for (int c = 0; c < 4; ++c) {                        \
                float4 qa = *(const float4*)(qr_ + c * 32 + cbase);                \
                float4 qb = *(const float4*)(qr_ + c * 32 + cbase + 4);            \
                part = fmaf(qa.x, (xr)[c][0], part); part = fmaf(qa.y, (xr)[c][1], part); \
                part = fmaf(qa.z, (xr)[c][2], part); part = fmaf(qa.w, (xr)[c][3], part); \
                part = fmaf(qb.x, (xr)[c][4], part); part = fmaf(qb.y, (xr)[c][5], part); \
                part = fmaf(qb.z, (xr)[c][6], part); part = fmaf(qb.w, (xr)[c][7], part); \
            }                                                                      \
            part += __shfl_xor(part, 16);                                          \
            part += __shfl_xor(part, 32);                                          \
            int kg_ = (ktile) + row;                                               \
            if (quad == 0 && kg_ < K) scores[(size_t)h * K + kg_] = part * 0.08838834764831845f; \
        }                                                                          \
        half8 af_[4];                                                              \
        _Pragma("unroll") for (int c = 0; c < 4; ++c)                              \
            _Pragma("unroll") for (int j = 0; j < 8; ++j) af_[c][j] = (_Float16)(xr)[c][j]; \
        f32x4 acc[8];                                                              \
        _Pragma("unroll") for (int nt = 0; nt < 8; ++nt) acc[nt] = (f32x4){0.f,0.f,0.f,0.f}; \
        _Pragma("unroll") for (int c = 0; c < 4; ++c)                              \
            _Pragma("unroll") for (int nt = 0; nt < 8; ++nt)                       \
                acc[nt] = __builtin_amdgcn_mfma_f32_16x16x32_f16(af_[c], PT1[c * 512 + nt * 64 + lane], acc[nt], 0, 0, 0); \
        _Pragma("unroll") for (int nt = 0; nt < 8; ++nt) {                         \
            const int n = nt * 16 + m;                                             \
            float b1v = hb1[h * 128 + n];                                          \
            _Pragma("unroll") for (int r = 0; r < 4; ++r) {                        \
                const int kk = wv * 16 + quad * 4 + r;                             \
                const int nn = n ^ ((kk & 7) << 2);                                \
                float t = acc[nt][r] + b1v;                                        \
                float x = XF[kk * 128 + nn];                                       \
                XF[kk * 128 + nn] = t / (1.f + expf(-t)) + x;                      \
            }                                                                      \
        }                                                                          \
        _Pragma("unroll") for (int nt = 0; nt < 8; ++nt) acc[nt] = (f32x4){0.f,0.f,0.f,0.f}; \
        _Pragma("unroll") for (int c = 0; c < 4; ++c) {                            \
            float4 f0 = *(const float4*)&XF[row * 128 + ((c * 32 + cbase) ^ sw)];  \
            float4 f1 = *(const float4*)&XF[row * 128 + ((c * 32 + cbase + 4) ^ sw)]; \
            half8 a2;                                                              \
            a2[0] = (_Float16)f0.x; a2[1] = (_Float16)f0.y;                        \
            a2[2] = (_Float16)f0.z; a2[3] = (_Float16)f0.w;                        \
            a2[4] = (_Float16)f1.x; a2[5] = (_Float16)f1.y;                        \
            a2[6] = (_Float16)f1.z; a2[7] = (_Float16)f1.w;                        \
            _Pragma("unroll") for (int nt = 0; nt < 8; ++nt)                       \
                acc[nt] = __builtin_amdgcn_mfma_f32_16x16x32_f16(a2, PT2[c * 512 + nt * 64 + lane], acc[nt], 0, 0, 0); \
        }                                                                          \
        {                                                                          \
            int ham[4] = {0, 0, 0, 0};                                             \
            _Pragma("unroll") for (int nt = 0; nt < 8; ++nt) {                     \
                const int n = nt * 16 + m;                                         \
                float b2v = hb2[h * 128 + n];                                      \
                _Pragma("unroll") for (int r = 0; r < 4; ++r) {                    \
                    const int kk = wv * 16 + quad * 4 + r;                         \
                    float t2 = acc[nt][r] + b2v + XF[kk * 128 + (n ^ ((kk & 7) << 2))]; \
                    unsigned long long bal = __ballot(t2 > 0.f);                   \
                    unsigned bits = (unsigned)(bal >> (quad * 16)) & 0xFFFFu;      \
                    ham[r] += __popc(bits ^ (unsigned)qh16[nt]);                   \
                }                                                                  \
            }                                                                      \
            if (m == 0) {                                                          \
                _Pragma("unroll") for (int r = 0; r < 4; ++r) {                    \
                    int kgd = (ktile) + wv * 16 + quad * 4 + r;                    \
                    if (kgd < K) draft[(size_t)h * K + kgd] = 128 - 2 * ham[r];    \
                }                                                                  \
            }                                                                      \
        }                                                                          \
    }

    const int kgA = k0 + row, kgB = k0 + 64 + row;

    // issue tile-A key loads, then tile-B key loads (HBM queue depth 2x),
    // then tile-A tables + rope (waits only on A loads).
    float xrA[4][8];
    LOAD_KEYS(kgA, xrA)
    float xvB[4][8];
    LOAD_KEYS(kgB, xvB)
    ROPE_INPLACE(kgA, xrA)

    unsigned short qh16[8];
    {
        uint4 q4 = *(const uint4*)((const unsigned*)(ws + OFF_QHASH) + h * 4);
        unsigned qa[4] = {q4.x, q4.y, q4.z, q4.w};
#pragma unroll
        for (int nt = 0; nt < 8; ++nt)
            qh16[nt] = (unsigned short)((qa[nt >> 1] >> ((nt & 1) * 16)) & 0xFFFFu);
    }

    PROCESS_TILE(xrA, k0)

    ROPE_INPLACE(kgB, xvB)
    PROCESS_TILE(xvB, k0 + 64)

#undef LOAD_KEYS
#undef ROPE_INPLACE
#undef PROCESS_TILE
}

// per head: exact stable top-k (histogram + index-ordered tie scan), write
// selected indices + softmax weights.
__global__ __launch_bounds__(256) void select_kernel(float* __restrict__ ws, int S, int nrem) {
    const int K = S + 1;
    const int h = blockIdx.x;
    const int tid = threadIdx.x;
    __shared__ int hist[129];
    __shared__ int sel_idx[512];
    __shared__ float red[256];
    __shared__ int wtot[4];
    __shared__ int sh_tval, sh_r, sh_cnt, sh_run;

    float* scoresB = ws + OFF_TAB + 2 * (size_t)K * 64;
    const int* draft = (const int*)(scoresB + (size_t)NH * K) + (size_t)h * K;
    const float* sc = scoresB + (size_t)h * K;
    float* attn = scoresB + 2 * (size_t)NH * K;
    int*   selidx_g = (int*)(attn + 4096) + h * 512;
    float* selw_g   = (attn + 4096 + NH * 512) + h * 512;

    for (int i = tid; i < 129; i += 256) hist[i] = 0;
    if (tid == 0) { sh_cnt = 0; sh_run = 0; }
    __syncthreads();
    for (int k = tid; k < K; k += 256) atomicAdd(&hist[(draft[k] + 128) >> 1], 1);
    __syncthreads();
    if (tid == 0) {
        int cum = 0, tb = 0, r = nrem;
        for (int b = 128; b >= 0; --b) {
            int c = hist[b];
            if (cum + c >= nrem) { tb = b; r = nrem - cum; break; }
            cum += c;
        }
        sh_tval = tb * 2 - 128; sh_r = r;
    }
    __syncthreads();
    const int tval = sh_tval, r = sh_r;
    const int lane = tid & 63, wave = tid >> 6;
    for (int base = 0; base < K; base += 256) {
        int k = base + tid;
        bool valid = (k < K);
        int dv = valid ? draft[k] : -1000;
        bool eq = valid && (dv == tval);
        bool gt = valid && (dv > tval);
        unsigned long long bal = __ballot(eq);
        if (lane == 0) wtot[wave] = __popcll(bal);
        __syncthreads();
        int woff = 0;
        for (int w = 0; w < wave; ++w) woff += wtot[w];
        int rank = sh_run + woff + __popcll(bal & ((1ull << lane) - 1ull));
        bool sel = gt || (eq && (rank < r));
        if (sel) sel_idx[atomicAdd(&sh_cnt, 1)] = k;
        __syncthreads();
        if (tid == 0) sh_run += wtot[0] + wtot[1] + wtot[2] + wtot[3];
        __syncthreads();
    }
    float mmax = -3.402823466e38f;
    for (int li = tid; li < nrem; li += 256) mmax = fmaxf(mmax, sc[sel_idx[li]]);
    red[tid] = mmax; __syncthreads();
    for (int s2 = 128; s2 > 0; s2 >>= 1) {
        if (tid < s2) red[tid] = fmaxf(red[tid], red[tid + s2]);
        __syncthreads();
    }
    mmax = red[0]; __syncthreads();
    float z = 0.f;
    for (int li = tid; li < nrem; li += 256) z += expf(sc[sel_idx[li]] - mmax);
    red[tid] = z; __syncthreads();
    for (int s2 = 128; s2 > 0; s2 >>= 1) {
        if (tid < s2) red[tid] += red[tid + s2];
        __syncthreads();
    }
    float Z = red[0]; __syncthreads();
    for (int li = tid; li < nrem; li += 256) {
        int idx = sel_idx[li];
        selidx_g[li] = idx;
        selw_g[li] = expf(sc[idx] - mmax) / Z;
    }
}

// weighted V gather: grid (NH,16); one wave per row (float2/lane = 512B row),
// 64 independent streams per head; atomic accum into attn. (r0-measured config)
__global__ __launch_bounds__(256) void gather_kernel(const float* __restrict__ val_cache,
        float* __restrict__ ws, int S, int nrem) {
    const int K = S + 1;
    const int h = blockIdx.x, g = blockIdx.y;
    const int tid = threadIdx.x;
    const int wave = tid >> 6, lane = tid & 63;
    const int stream = g * 4 + wave;
    float* scoresB = ws + OFF_TAB + 2 * (size_t)K * 64;
    float* attn = scoresB + 2 * (size_t)NH * K;
    const int*   selidx_g = (const int*)(attn + 4096) + h * 512;
    const float* selw_g   = (attn + 4096 + NH * 512) + h * 512;
    float ax = 0.f, ay = 0.f;
    for (int li = stream; li < nrem; li += 64) {
        int idx = selidx_g[li];
        float w = selw_g[li];
        const float* vr = (idx < S) ? val_cache + ((size_t)h * S + idx) * 128
                                    : ws + OFF_VNEW + (h >> 2) * 128;
        float2 v = ((const float2*)vr)[lane];
        ax = fmaf(w, v.x, ax);
        ay = fmaf(w, v.y, ay);
    }
    atomicAdd(&attn[h * 128 + lane * 2 + 0], ax);
    atomicAdd(&attn[h * 128 + lane * 2 + 1], ay);
}

// attn(4096) @ Wo(4096x4096) -> out. float4 cols, 64-row split-K, atomics.
// (r0-measured config)
__global__ __launch_bounds__(256) void out_gemv(const float* __restrict__ Wo,
        const float* __restrict__ ws, float* __restrict__ out, int K) {
    __shared__ float hs[64];
    const int tid = threadIdx.x;
    const int col = (blockIdx.x * 256 + tid) * 4;
    const int i0  = blockIdx.y * 64;
    const float* ao = ws + OFF_TAB + 2 * (size_t)K * 64 + 2 * (size_t)NH * K;
    if (tid < 64) hs[tid] = ao[i0 + tid];
    __syncthreads();
    const float* p = Wo + (size_t)i0 * 4096 + col;
    float4 a0 = {0.f,0.f,0.f,0.f}, a1 = {0.f,0.f,0.f,0.f};
#pragma unroll 4
    for (int ii = 0; ii < 64; ii += 2) {
        float4 w0 = *(const float4*)p;
        float4 w1 = *(const float4*)(p + 4096);
        float h0 = hs[ii], h1 = hs[ii + 1];
        a0.x = fmaf(h0, w0.x, a0.x); a0.y = fmaf(h0, w0.y, a0.y);
        a0.z = fmaf(h0, w0.z, a0.z); a0.w = fmaf(h0, w0.w, a0.w);
        a1.x = fmaf(h1, w1.x, a1.x); a1.y = fmaf(h1, w1.y, a1.y);
        a1.z = fmaf(h1, w1.z, a1.z); a1.w = fmaf(h1, w1.w, a1.w);
        p += 8192;
    }
    atomicAdd(&out[col + 0], a0.x + a1.x);
    atomicAdd(&out[col + 1], a0.y + a1.y);
    atomicAdd(&out[col + 2], a0.z + a1.z);
    atomicAdd(&out[col + 3], a0.w + a1.w);
}

extern "C" void kernel_launch(void* const* d_in, const int* in_sizes, int n_in,
                              void* d_out, int out_size, void* d_ws, size_t ws_size,
                              hipStream_t stream) {
    const float* hidden = (const float*)d_in[0];
    const float* key_cache = (const float*)d_in[1];
    const float* val_cache = (const float*)d_in[2];
    const float* Wq = (const float*)d_in[3];
    const float* Wk = (const float*)d_in[4];
    const float* Wv = (const float*)d_in[5];
    const float* Wo = (const float*)d_in[6];
    const float* hp1 = (const float*)d_in[7];
    const float* hb1 = (const float*)d_in[8];
    const float* hp2 = (const float*)d_in[9];
    const float* hb2 = (const float*)d_in[10];
    float* out = (float*)d_out;
    float* ws  = (float*)d_ws;

    const int S = in_sizes[1] / (NH * HD);   // 4096
    const int K = S + 1;                      // 4097
    int mn = (K < 128) ? K : 128;
    int nrem = K - (int)((double)K * 0.9);
    if (nrem < mn) nrem = mn;                 // 410

    const int nInit = (K * 64 + 255) / 256;
    init_kernel<<<nInit + 512, 256, 0, stream>>>(hp1, hp2, ws, out, K, nInit);
    qkv_gemv<<<dim3(6, 64), 256, 0, stream>>>(hidden, Wq, Wk, Wv, ws);
    qhash_kernel<<<NH, 128, 0, stream>>>(hp1, hb1, hp2, hb2, ws, S);
    key_kernel<<<dim3((K + 127) / 128, NH), 256, 0, stream>>>(key_cache, hb1, hb2, ws, S);
    select_kernel<<<NH, 256, 0, stream>>>(ws, S, nrem);
    gather_kernel<<<dim3(NH, 16), 256, 0, stream>>>(val_cache, ws, S, nrem);
    out_gemv<<<dim3(4, 64), 256, 0, stream>>>(Wo, ws, out, K);
}

// Round 3
// 354.433 us; speedup vs baseline: 1.2455x; 1.2455x over previous
//
#include <hip/hip_runtime.h>
#include <math.h>

#define NH 32
#define NKVH 8
#define HD 128

typedef _Float16 half8 __attribute__((ext_vector_type(8)));
typedef float f32x4 __attribute__((ext_vector_type(4)));

// ws layout (float elements):
#define OFF_QPROJ 0        // 4096 q | 1024 k | 1024 v
#define OFF_KNEW  4096
#define OFF_VNEW  5120
#define OFF_QR    6144     // 4096
#define OFF_QHASH 10240    // 128 (32x u32)
#define OFF_TAB   10368    // cos K*64 | sin K*64
// OFF_SCORES = OFF_TAB + 2*K*64        (NH*K floats)
// OFF_DRAFT  = OFF_SCORES + NH*K       (NH*K int)
// OFF_ATTN   = OFF_DRAFT + NH*K        (4096)
// OFF_SELIDX = OFF_ATTN + 4096         (NH*512 int)
// OFF_SELW   = OFF_SELIDX + NH*512     (NH*512)
// OFF_PT16   = OFF_SELW + NH*512       (NH*2*16384 fp16)

// combined: rope tables + zero-init (blocks < nInit), PT16 weight transpose
// (blocks >= nInit). PT16[h][mat][ks(4)][nt(8)][lane(64)][j(8)] =
// P[h][k=ks*32+(lane>>4)*8+j][n=nt*16+(lane&15)]
__global__ void init_kernel(const float* __restrict__ hp1, const float* __restrict__ hp2,
                            float* __restrict__ ws, float* __restrict__ out,
                            int K, int nInit) {
    const int tid = threadIdx.x;
    if ((int)blockIdx.x < nInit) {
        int idx = blockIdx.x * 256 + tid;
        if (idx < K * 64) {
            int pos = idx >> 6, d = idx & 63;
            double inv = exp(-((double)d / 64.0) * log(10000.0));
            double ang = (double)pos * inv;
            double s, c;
            sincos(ang, &s, &c);
            ws[OFF_TAB + idx]                  = (float)c;
            ws[OFF_TAB + (size_t)K * 64 + idx] = (float)s;
        }
        if (idx < 6144) ws[OFF_QPROJ + idx] = 0.f;
        if (idx < 4096) out[idx] = 0.f;
        size_t off_attn = OFF_TAB + 2 * (size_t)K * 64 + 2 * (size_t)NH * K;
        if (idx < 4096) ws[off_attn + idx] = 0.f;
    } else {
        int id = blockIdx.x - nInit;          // 0..511
        int h2 = id >> 3;                     // 0..63  (h*2+mat)
        int tg = (id & 7) * 256 + tid;        // 0..2047
        const int lane = tg & 63, nt = (tg >> 6) & 7, ks = tg >> 9;
        const int kbase = ks * 32 + ((tg >> 4) & 3) * 8;
        const int n = nt * 16 + (tg & 15);
        const float* P = ((h2 & 1) ? hp2 : hp1) + (size_t)(h2 >> 1) * 16384;
        half8 v;
#pragma unroll
        for (int j = 0; j < 8; ++j) v[j] = (_Float16)P[(size_t)(kbase + j) * 128 + n];
        size_t off_pt = OFF_TAB + 2 * (size_t)K * 64 + 2 * (size_t)NH * K + 4096 + 2 * (size_t)NH * 512;
        ((half8*)(ws + off_pt))[(size_t)h2 * 2048 + tg] = v;
    }
}

// hidden(4096) @ [Wq|Wk|Wv] -> qproj(6144). float4 cols, 64-row split-K, atomics.
// (r0-measured config; y=128 doubled atomic contention and regressed)
__global__ __launch_bounds__(256) void qkv_gemv(const float* __restrict__ hidden,
        const float* __restrict__ Wq, const float* __restrict__ Wk,
        const float* __restrict__ Wv, float* __restrict__ ws) {
    __shared__ float hs[64];
    const int tid = threadIdx.x;
    const int col = (blockIdx.x * 256 + tid) * 4;
    const int i0  = blockIdx.y * 64;
    if (tid < 64) hs[tid] = hidden[i0 + tid];
    __syncthreads();
    const float* W; int ld, wcol;
    if (col < 4096)      { W = Wq; ld = 4096; wcol = col; }
    else if (col < 5120) { W = Wk; ld = 1024; wcol = col - 4096; }
    else                 { W = Wv; ld = 1024; wcol = col - 5120; }
    const float* p = W + (size_t)i0 * ld + wcol;
    float4 a0 = {0.f,0.f,0.f,0.f}, a1 = {0.f,0.f,0.f,0.f};
#pragma unroll 4
    for (int ii = 0; ii < 64; ii += 2) {
        float4 w0 = *(const float4*)p;
        float4 w1 = *(const float4*)(p + ld);
        float h0 = hs[ii], h1 = hs[ii + 1];
        a0.x = fmaf(h0, w0.x, a0.x); a0.y = fmaf(h0, w0.y, a0.y);
        a0.z = fmaf(h0, w0.z, a0.z); a0.w = fmaf(h0, w0.w, a0.w);
        a1.x = fmaf(h1, w1.x, a1.x); a1.y = fmaf(h1, w1.y, a1.y);
        a1.z = fmaf(h1, w1.z, a1.z); a1.w = fmaf(h1, w1.w, a1.w);
        p += 2 * (size_t)ld;
    }
    atomicAdd(&ws[OFF_QPROJ + col + 0], a0.x + a1.x);
    atomicAdd(&ws[OFF_QPROJ + col + 1], a0.y + a1.y);
    atomicAdd(&ws[OFF_QPROJ + col + 2], a0.z + a1.z);
    atomicAdd(&ws[OFF_QPROJ + col + 3], a0.w + a1.w);
}

// per head: rope(q), hash(q) in fp32, pack sign bits
__global__ __launch_bounds__(128) void qhash_kernel(const float* __restrict__ hp1,
        const float* __restrict__ hb1, const float* __restrict__ hp2,
        const float* __restrict__ hb2, float* __restrict__ ws, int S) {
    const int h = blockIdx.x, d = threadIdx.x;
    const int K = S + 1;
    __shared__ float X[128], H1[128];
    float q  = ws[OFF_QPROJ + h * 128 + d];
    float qp = ws[OFF_QPROJ + h * 128 + (d ^ 64)];
    const float* cosT = ws + OFF_TAB;
    const float* sinT = cosT + (size_t)K * 64;
    float cs = cosT[(size_t)S * 64 + (d & 63)];
    float sn = sinT[(size_t)S * 64 + (d & 63)];
    float r = (d < 64) ? -qp : qp;
    float qr = q * cs + r * sn;
    X[d] = qr;
    ws[OFF_QR + h * 128 + d] = qr;
    __syncthreads();
    const float* P1 = hp1 + (size_t)h * 16384;
    float t = hb1[h * 128 + d];
    for (int i = 0; i < 128; ++i) t = fmaf(X[i], P1[i * 128 + d], t);
    float u = t / (1.f + expf(-t)) + X[d];
    H1[d] = u;
    __syncthreads();
    const float* P2 = hp2 + (size_t)h * 16384;
    float t2 = hb2[h * 128 + d] + u;
    for (int i = 0; i < 128; ++i) t2 = fmaf(H1[i], P2[i * 128 + d], t2);
    unsigned long long bal = __ballot(t2 > 0.f);
    if ((d & 63) == 0)
        ((unsigned long long*)(ws + OFF_QHASH))[h * 2 + (d >> 6)] = bal;
}

// MFMA key kernel, barrier-free: 64 keys/block, everything wave-local.
// r1 structure (no multi-tile pipelining — r2 proved it spills at this reg
// budget) + r2's XOR-swizzled stride-128 XF (32 KiB LDS, ~2-way banks).
// amdgpu_waves_per_eu(4,5): LDS already caps occupancy at 5 blocks/CU, so
// let the allocator use up to 128 VGPRs for load-pipelining instead of
// squeezing to 64 for an occupancy it can never reach.
__global__ __launch_bounds__(256) __attribute__((amdgpu_waves_per_eu(4, 5)))
void key_kernel(const float* __restrict__ key_cache,
        const float* __restrict__ hb1, const float* __restrict__ hb2,
        float* __restrict__ ws, int S) {
    const int K  = S + 1;
    const int h  = blockIdx.y;
    const int k0 = blockIdx.x * 64;
    const int tid = threadIdx.x;
    const int wv = tid >> 6, lane = tid & 63;
    const int m = lane & 15, quad = lane >> 4;
    const int row = wv * 16 + m;
    const int cbase = quad * 8;
    const int sw = (m & 7) << 2;          // XOR swizzle: f(row,col)=col^((row&7)<<2)

    __shared__ float XF[64 * 128];        // 32 KiB

    const float* cosT = ws + OFF_TAB;
    const float* sinT = cosT + (size_t)K * 64;
    float* scores = ws + OFF_TAB + 2 * (size_t)K * 64;
    int*   draft  = (int*)(scores + (size_t)NH * K);
    size_t off_pt = OFF_TAB + 2 * (size_t)K * 64 + 2 * (size_t)NH * K + 4096 + 2 * (size_t)NH * 512;
    const half8* PT1 = (const half8*)((const _Float16*)(ws + off_pt) + (size_t)(h * 2) * 16384);
    const half8* PT2 = PT1 + 2048;

    const int kg = k0 + row;

    // ---- issue key loads first (HBM, longest latency) ----
    float xr[4][8];
    if (kg < K) {
        const float* krow = (kg < S) ? key_cache + ((size_t)h * S + kg) * 128
                                     : ws + OFF_KNEW + (h >> 2) * 128;
#pragma unroll
        for (int c = 0; c < 4; ++c) {
            *(float4*)&xr[c][0] = *(const float4*)(krow + c * 32 + cbase);
            *(float4*)&xr[c][4] = *(const float4*)(krow + c * 32 + cbase + 4);
        }
    } else {
#pragma unroll
        for (int c = 0; c < 4; ++c)
#pragma unroll
            for (int j = 0; j < 8; ++j) xr[c][j] = 0.f;
    }

    // ---- independent small loads early: biases, q-hash ----
    float b1v[8], b2v[8];
#pragma unroll
    for (int nt = 0; nt < 8; ++nt) {
        b1v[nt] = hb1[h * 128 + nt * 16 + m];
        b2v[nt] = hb2[h * 128 + nt * 16 + m];
    }
    unsigned short qh16[8];
    {
        uint4 q4 = *(const uint4*)((const unsigned*)(ws + OFF_QHASH) + h * 4);
        unsigned qa[4] = {q4.x, q4.y, q4.z, q4.w};
#pragma unroll
        for (int nt = 0; nt < 8; ++nt)
            qh16[nt] = (unsigned short)((qa[nt >> 1] >> ((nt & 1) * 16)) & 0xFFFFu);
    }

    // ---- rope in-place ----
    if (kg < K) {
        float cc[2][8], ss[2][8];
#pragma unroll
        for (int c = 0; c < 2; ++c) {
            *(float4*)&cc[c][0] = *(const float4*)(cosT + (size_t)kg * 64 + c * 32 + cbase);
            *(float4*)&cc[c][4] = *(const float4*)(cosT + (size_t)kg * 64 + c * 32 + cbase + 4);
            *(float4*)&ss[c][0] = *(const float4*)(sinT + (size_t)kg * 64 + c * 32 + cbase);
            *(float4*)&ss[c][4] = *(const float4*)(sinT + (size_t)kg * 64 + c * 32 + cbase + 4);
        }
#pragma unroll
        for (int c = 0; c < 2; ++c)
#pragma unroll
            for (int j = 0; j < 8; ++j) {
                float lo = xr[c][j]     * cc[c][j] - xr[c + 2][j] * ss[c][j];
                float hi = xr[c + 2][j] * cc[c][j] + xr[c][j]     * ss[c][j];
                xr[c][j] = lo; xr[c + 2][j] = hi;
            }
    }

    // ---- residual to LDS (swizzled); wave-local rows only, no barrier ----
#pragma unroll
    for (int c = 0; c < 4; ++c) {
        *(float4*)&XF[row * 128 + ((c * 32 + cbase) ^ sw)]     = *(float4*)&xr[c][0];
        *(float4*)&XF[row * 128 + ((c * 32 + cbase + 4) ^ sw)] = *(float4*)&xr[c][4];
    }

    // ---- true attention score (fp32, q straight from L2) ----
    {
        const float* qr = ws + OFF_QR + h * 128;
        float part = 0.f;
#pragma unroll
        for (int c = 0; c < 4; ++c) {
            float4 qa = *(const float4*)(qr + c * 32 + cbase);
            float4 qb = *(const float4*)(qr + c * 32 + cbase + 4);
            part = fmaf(qa.x, xr[c][0], part); part = fmaf(qa.y, xr[c][1], part);
            part = fmaf(qa.z, xr[c][2], part); part = fmaf(qa.w, xr[c][3], part);
            part = fmaf(qb.x, xr[c][4], part); part = fmaf(qb.y, xr[c][5], part);
            part = fmaf(qb.z, xr[c][6], part); part = fmaf(qb.w, xr[c][7], part);
        }
        part += __shfl_xor(part, 16);
        part += __shfl_xor(part, 32);
        if (quad == 0 && kg < K) scores[(size_t)h * K + kg] = part * 0.08838834764831845f;
    }

    // ---- fp16 A fragments for GEMM1 (register-direct) ----
    half8 af[4];
#pragma unroll
    for (int c = 0; c < 4; ++c)
#pragma unroll
        for (int j = 0; j < 8; ++j) af[c][j] = (_Float16)xr[c][j];

    f32x4 acc[8];

    // ---- GEMM1: t1 = X@P1 (B fragments from L2) ----
#pragma unroll
    for (int nt = 0; nt < 8; ++nt) acc[nt] = (f32x4){0.f, 0.f, 0.f, 0.f};
#pragma unroll
    for (int c = 0; c < 4; ++c)
#pragma unroll
        for (int nt = 0; nt < 8; ++nt)
            acc[nt] = __builtin_amdgcn_mfma_f32_16x16x32_f16(af[c], PT1[c * 512 + nt * 64 + lane], acc[nt], 0, 0, 0);

    // epilogue1: h1 = silu(t1+b1) + x  (per-lane RMW on XF at C-layout)
#pragma unroll
    for (int nt = 0; nt < 8; ++nt) {
        const int n = nt * 16 + m;
#pragma unroll
        for (int r = 0; r < 4; ++r) {
            const int kk = wv * 16 + quad * 4 + r;
            const int nn = n ^ ((kk & 7) << 2);
            float t = acc[nt][r] + b1v[nt];
            float x = XF[kk * 128 + nn];
            XF[kk * 128 + nn] = t / (1.f + expf(-t)) + x;
        }
    }

    // ---- GEMM2: t2 = H1@P2; A-frags read fp32 from XF, converted in regs ----
#pragma unroll
    for (int nt = 0; nt < 8; ++nt) acc[nt] = (f32x4){0.f, 0.f, 0.f, 0.f};
#pragma unroll
    for (int c = 0; c < 4; ++c) {
        float4 f0 = *(const float4*)&XF[row * 128 + ((c * 32 + cbase) ^ sw)];
        float4 f1 = *(const float4*)&XF[row * 128 + ((c * 32 + cbase + 4) ^ sw)];
        half8 a2;
        a2[0] = (_Float16)f0.x; a2[1] = (_Float16)f0.y;
        a2[2] = (_Float16)f0.z; a2[3] = (_Float16)f0.w;
        a2[4] = (_Float16)f1.x; a2[5] = (_Float16)f1.y;
        a2[6] = (_Float16)f1.z; a2[7] = (_Float16)f1.w;
#pragma unroll
        for (int nt = 0; nt < 8; ++nt)
            acc[nt] = __builtin_amdgcn_mfma_f32_16x16x32_f16(a2, PT2[c * 512 + nt * 64 + lane], acc[nt], 0, 0, 0);
    }

    // epilogue2: t2 += b2 + h1 ; ballot sign-pack ; popcount draft
    {
        int ham[4] = {0, 0, 0, 0};
#pragma unroll
        for (int nt = 0; nt < 8; ++nt) {
            const int n = nt * 16 + m;
#pragma unroll
            for (int r = 0; r < 4; ++r) {
                const int kk = wv * 16 + quad * 4 + r;
                float t2 = acc[nt][r] + b2v[nt] + XF[kk * 128 + (n ^ ((kk & 7) << 2))];
                unsigned long long bal = __ballot(t2 > 0.f);
                unsigned bits = (unsigned)(bal >> (quad * 16)) & 0xFFFFu;
                ham[r] += __popc(bits ^ (unsigned)qh16[nt]);
            }
        }
        if (m == 0) {
#pragma unroll
            for (int r = 0; r < 4; ++r) {
                int kgd = k0 + wv * 16 + quad * 4 + r;
                if (kgd < K) draft[(size_t)h * K + kgd] = 128 - 2 * ham[r];
            }
        }
    }
}

// per head: exact stable top-k (histogram + index-ordered tie scan), write
// selected indices + softmax weights.
__global__ __launch_bounds__(256) void select_kernel(float* __restrict__ ws, int S, int nrem) {
    const int K = S + 1;
    const int h = blockIdx.x;
    const int tid = threadIdx.x;
    __shared__ int hist[129];
    __shared__ int sel_idx[512];
    __shared__ float red[256];
    __shared__ int wtot[4];
    __shared__ int sh_tval, sh_r, sh_cnt, sh_run;

    float* scoresB = ws + OFF_TAB + 2 * (size_t)K * 64;
    const int* draft = (const int*)(scoresB + (size_t)NH * K) + (size_t)h * K;
    const float* sc = scoresB + (size_t)h * K;
    float* attn = scoresB + 2 * (size_t)NH * K;
    int*   selidx_g = (int*)(attn + 4096) + h * 512;
    float* selw_g   = (attn + 4096 + NH * 512) + h * 512;

    for (int i = tid; i < 129; i += 256) hist[i] = 0;
    if (tid == 0) { sh_cnt = 0; sh_run = 0; }
    __syncthreads();
    for (int k = tid; k < K; k += 256) atomicAdd(&hist[(draft[k] + 128) >> 1], 1);
    __syncthreads();
    if (tid == 0) {
        int cum = 0, tb = 0, r = nrem;
        for (int b = 128; b >= 0; --b) {
            int c = hist[b];
            if (cum + c >= nrem) { tb = b; r = nrem - cum; break; }
            cum += c;
        }
        sh_tval = tb * 2 - 128; sh_r = r;
    }
    __syncthreads();
    const int tval = sh_tval, r = sh_r;
    const int lane = tid & 63, wave = tid >> 6;
    for (int base = 0; base < K; base += 256) {
        int k = base + tid;
        bool valid = (k < K);
        int dv = valid ? draft[k] : -1000;
        bool eq = valid && (dv == tval);
        bool gt = valid && (dv > tval);
        unsigned long long bal = __ballot(eq);
        if (lane == 0) wtot[wave] = __popcll(bal);
        __syncthreads();
        int woff = 0;
        for (int w = 0; w < wave; ++w) woff += wtot[w];
        int rank = sh_run + woff + __popcll(bal & ((1ull << lane) - 1ull));
        bool sel = gt || (eq && (rank < r));
        if (sel) sel_idx[atomicAdd(&sh_cnt, 1)] = k;
        __syncthreads();
        if (tid == 0) sh_run += wtot[0] + wtot[1] + wtot[2] + wtot[3];
        __syncthreads();
    }
    float mmax = -3.402823466e38f;
    for (int li = tid; li < nrem; li += 256) mmax = fmaxf(mmax, sc[sel_idx[li]]);
    red[tid] = mmax; __syncthreads();
    for (int s2 = 128; s2 > 0; s2 >>= 1) {
        if (tid < s2) red[tid] = fmaxf(red[tid], red[tid + s2]);
        __syncthreads();
    }
    mmax = red[0]; __syncthreads();
    float z = 0.f;
    for (int li = tid; li < nrem; li += 256) z += expf(sc[sel_idx[li]] - mmax);
    red[tid] = z; __syncthreads();
    for (int s2 = 128; s2 > 0; s2 >>= 1) {
        if (tid < s2) red[tid] += red[tid + s2];
        __syncthreads();
    }
    float Z = red[0]; __syncthreads();
    for (int li = tid; li < nrem; li += 256) {
        int idx = sel_idx[li];
        selidx_g[li] = idx;
        selw_g[li] = expf(sc[idx] - mmax) / Z;
    }
}

// weighted V gather: grid (NH,16); one wave per row (float2/lane = 512B row),
// 64 independent streams per head; atomic accum into attn. (r0-measured config)
__global__ __launch_bounds__(256) void gather_kernel(const float* __restrict__ val_cache,
        float* __restrict__ ws, int S, int nrem) {
    const int K = S + 1;
    const int h = blockIdx.x, g = blockIdx.y;
    const int tid = threadIdx.x;
    const int wave = tid >> 6, lane = tid & 63;
    const int stream = g * 4 + wave;
    float* scoresB = ws + OFF_TAB + 2 * (size_t)K * 64;
    float* attn = scoresB + 2 * (size_t)NH * K;
    const int*   selidx_g = (const int*)(attn + 4096) + h * 512;
    const float* selw_g   = (attn + 4096 + NH * 512) + h * 512;
    float ax = 0.f, ay = 0.f;
    for (int li = stream; li < nrem; li += 64) {
        int idx = selidx_g[li];
        float w = selw_g[li];
        const float* vr = (idx < S) ? val_cache + ((size_t)h * S + idx) * 128
                                    : ws + OFF_VNEW + (h >> 2) * 128;
        float2 v = ((const float2*)vr)[lane];
        ax = fmaf(w, v.x, ax);
        ay = fmaf(w, v.y, ay);
    }
    atomicAdd(&attn[h * 128 + lane * 2 + 0], ax);
    atomicAdd(&attn[h * 128 + lane * 2 + 1], ay);
}

// attn(4096) @ Wo(4096x4096) -> out. float4 cols, 64-row split-K, atomics.
// (r0-measured config)
__global__ __launch_bounds__(256) void out_gemv(const float* __restrict__ Wo,
        const float* __restrict__ ws, float* __restrict__ out, int K) {
    __shared__ float hs[64];
    const int tid = threadIdx.x;
    const int col = (blockIdx.x * 256 + tid) * 4;
    const int i0  = blockIdx.y * 64;
    const float* ao = ws + OFF_TAB + 2 * (size_t)K * 64 + 2 * (size_t)NH * K;
    if (tid < 64) hs[tid] = ao[i0 + tid];
    __syncthreads();
    const float* p = Wo + (size_t)i0 * 4096 + col;
    float4 a0 = {0.f,0.f,0.f,0.f}, a1 = {0.f,0.f,0.f,0.f};
#pragma unroll 4
    for (int ii = 0; ii < 64; ii += 2) {
        float4 w0 = *(const float4*)p;
        float4 w1 = *(const float4*)(p + 4096);
        float h0 = hs[ii], h1 = hs[ii + 1];
        a0.x = fmaf(h0, w0.x, a0.x); a0.y = fmaf(h0, w0.y, a0.y);
        a0.z = fmaf(h0, w0.z, a0.z); a0.w = fmaf(h0, w0.w, a0.w);
        a1.x = fmaf(h1, w1.x, a1.x); a1.y = fmaf(h1, w1.y, a1.y);
        a1.z = fmaf(h1, w1.z, a1.z); a1.w = fmaf(h1, w1.w, a1.w);
        p += 8192;
    }
    atomicAdd(&out[col + 0], a0.x + a1.x);
    atomicAdd(&out[col + 1], a0.y + a1.y);
    atomicAdd(&out[col + 2], a0.z + a1.z);
    atomicAdd(&out[col + 3], a0.w + a1.w);
}

extern "C" void kernel_launch(void* const* d_in, const int* in_sizes, int n_in,
                              void* d_out, int out_size, void* d_ws, size_t ws_size,
                              hipStream_t stream) {
    const float* hidden = (const float*)d_in[0];
    const float* key_cache = (const float*)d_in[1];
    const float* val_cache = (const float*)d_in[2];
    const float* Wq = (const float*)d_in[3];
    const float* Wk = (const float*)d_in[4];
    const float* Wv = (const float*)d_in[5];
    const float* Wo = (const float*)d_in[6];
    const float* hp1 = (const float*)d_in[7];
    const float* hb1 = (const float*)d_in[8];
    const float* hp2 = (const float*)d_in[9];
    const float* hb2 = (const float*)d_in[10];
    float* out = (float*)d_out;
    float* ws  = (float*)d_ws;

    const int S = in_sizes[1] / (NH * HD);   // 4096
    const int K = S + 1;                      // 4097
    int mn = (K < 128) ? K : 128;
    int nrem = K - (int)((double)K * 0.9);
    if (nrem < mn) nrem = mn;                 // 410

    const int nInit = (K * 64 + 255) / 256;
    init_kernel<<<nInit + 512, 256, 0, stream>>>(hp1, hp2, ws, out, K, nInit);
    qkv_gemv<<<dim3(6, 64), 256, 0, stream>>>(hidden, Wq, Wk, Wv, ws);
    qhash_kernel<<<NH, 128, 0, stream>>>(hp1, hb1, hp2, hb2, ws, S);
    key_kernel<<<dim3((K + 63) / 64, NH), 256, 0, stream>>>(key_cache, hb1, hb2, ws, S);
    select_kernel<<<NH, 256, 0, stream>>>(ws, S, nrem);
    gather_kernel<<<dim3(NH, 16), 256, 0, stream>>>(val_cache, ws, S, nrem);
    out_gemv<<<dim3(4, 64), 256, 0, stream>>>(Wo, ws, out, K);
}